// Round 1
// baseline (16230.180 us; speedup 1.0000x reference)
//
#include <hip/hip_runtime.h>

#define D_FEAT 128

// h[i] = x[i]  (vectorized copy)
__global__ void init_h0(const float4* __restrict__ x, float4* __restrict__ h, int n4) {
    int i = blockIdx.x * blockDim.x + threadIdx.x;
    if (i < n4) h[i] = x[i];
}

// h[idx[r]] += x_id[r]   (atomic: idx may contain duplicates)
// 32 threads per row, float4 per thread
__global__ void scatter_id(const float4* __restrict__ x_id, const int* __restrict__ idx,
                           float* __restrict__ h, int n) {
    int t = blockIdx.x * blockDim.x + threadIdx.x;
    int r = t >> 5;
    int q = t & 31;
    if (r < n) {
        float4 v = x_id[r * 32 + q];
        float* o = h + (size_t)idx[r] * D_FEAT + q * 4;
        atomicAdd(o + 0, v.x);
        atomicAdd(o + 1, v.y);
        atomicAdd(o + 2, v.z);
        atomicAdd(o + 3, v.w);
    }
}

// out[row[e]] += h[col[e]]  for all edges; 32 threads/edge, float4 loads
__global__ void edge_scatter(const int* __restrict__ row, const int* __restrict__ col,
                             const float4* __restrict__ h, float* __restrict__ out, int nE) {
    int t = blockIdx.x * blockDim.x + threadIdx.x;
    int e = t >> 5;
    int q = t & 31;
    if (e < nE) {
        int r = row[e];
        int c = col[e];
        float4 v = h[c * 32 + q];
        float* o = out + (size_t)r * D_FEAT + q * 4;
        atomicAdd(o + 0, v.x);
        atomicAdd(o + 1, v.y);
        atomicAdd(o + 2, v.z);
        atomicAdd(o + 3, v.w);
    }
}

extern "C" void kernel_launch(void* const* d_in, const int* in_sizes, int n_in,
                              void* d_out, int out_size, void* d_ws, size_t ws_size,
                              hipStream_t stream) {
    const float* x    = (const float*)d_in[0];
    const float* x_id = (const float*)d_in[1];
    const int*   edge = (const int*)d_in[2];   // [2, nE] flattened: row then col
    const int*   idx  = (const int*)d_in[3];
    // d_in[4] is K (always 3 for this problem; reading device scalar would need a sync)

    int nE = in_sizes[2] / 2;
    int nN = in_sizes[3];

    const int* row = edge;
    const int* col = edge + nE;

    float* out = (float*)d_out;
    float* ws  = (float*)d_ws;   // needs nN*128*4 = 51.2 MB

    size_t hbytes = (size_t)nN * D_FEAT * sizeof(float);

    // ---- h0 = x (+ scatter x_id at idx) -> ws ----
    int n4 = nN * D_FEAT / 4;
    hipLaunchKernelGGL(init_h0, dim3((n4 + 255) / 256), dim3(256), 0, stream,
                       (const float4*)x, (float4*)ws, n4);
    {
        int tot = nN * 32;
        hipLaunchKernelGGL(scatter_id, dim3((tot + 255) / 256), dim3(256), 0, stream,
                           (const float4*)x_id, idx, ws, nN);
    }

    // edge grid: nE edges * 32 threads each
    long long totE = (long long)nE * 32;
    unsigned int gE = (unsigned int)((totE + 255) / 256);

    // ---- hop 1: ws -> out ----
    hipMemsetAsync(out, 0, hbytes, stream);
    hipLaunchKernelGGL(edge_scatter, dim3(gE), dim3(256), 0, stream,
                       row, col, (const float4*)ws, out, nE);

    // ---- hop 2: out -> ws ----
    hipMemsetAsync(ws, 0, hbytes, stream);
    hipLaunchKernelGGL(edge_scatter, dim3(gE), dim3(256), 0, stream,
                       row, col, (const float4*)out, ws, nE);

    // ---- hop 3: ws -> out ----
    hipMemsetAsync(out, 0, hbytes, stream);
    hipLaunchKernelGGL(edge_scatter, dim3(gE), dim3(256), 0, stream,
                       row, col, (const float4*)ws, out, nE);
}

// Round 2
// 1263.990 us; speedup vs baseline: 12.8404x; 12.8404x over previous
//
#include <hip/hip_runtime.h>

#define D_FEAT 128

// ---------------- common small kernels ----------------

__global__ void init_h0(const float4* __restrict__ x, float4* __restrict__ h, int n4) {
    int i = blockIdx.x * blockDim.x + threadIdx.x;
    if (i < n4) h[i] = x[i];
}

// h[idx[r]] += x_id[r]  (atomic; idx may contain duplicates). 32 thr/row, float4.
__global__ void scatter_id(const float4* __restrict__ x_id, const int* __restrict__ idx,
                           float* __restrict__ h, int n) {
    int t = blockIdx.x * blockDim.x + threadIdx.x;
    int r = t >> 5;
    int q = t & 31;
    if (r < n) {
        float4 v = x_id[r * 32 + q];
        float* o = h + (size_t)idx[r] * D_FEAT + q * 4;
        atomicAdd(o + 0, v.x);
        atomicAdd(o + 1, v.y);
        atomicAdd(o + 2, v.z);
        atomicAdd(o + 3, v.w);
    }
}

// ---------------- CSR build ----------------

__global__ void hist_rows(const int* __restrict__ row, int* __restrict__ deg, int nE) {
    int e = blockIdx.x * blockDim.x + threadIdx.x;
    if (e < nE) atomicAdd(&deg[row[e]], 1);
}

// per-256-block exclusive scan of deg -> ptr (partial); bsum[b] = block total
__global__ void scan_blocks(const int* __restrict__ deg, int* __restrict__ ptrOut,
                            int* __restrict__ bsum, int n) {
    __shared__ int s[256];
    int t = threadIdx.x;
    int i = blockIdx.x * 256 + t;
    int v = (i < n) ? deg[i] : 0;
    s[t] = v;
    __syncthreads();
    for (int off = 1; off < 256; off <<= 1) {
        int add = (t >= off) ? s[t - off] : 0;
        __syncthreads();
        s[t] += add;
        __syncthreads();
    }
    if (i < n) ptrOut[i] = s[t] - v;   // exclusive
    if (t == 255) bsum[blockIdx.x] = s[255];
}

// single-block exclusive scan of bsum (nb <= 1024)
__global__ void scan_bsums(int* __restrict__ bsum, int nb) {
    __shared__ int s[1024];
    int t = threadIdx.x;
    int v = (t < nb) ? bsum[t] : 0;
    s[t] = v;
    __syncthreads();
    for (int off = 1; off < 1024; off <<= 1) {
        int add = (t >= off) ? s[t - off] : 0;
        __syncthreads();
        s[t] += add;
        __syncthreads();
    }
    if (t < nb) bsum[t] = s[t] - v;    // exclusive
}

// ptr[i] += bsum[i/256]; next[i] = ptr[i]; ptr[n] = nE
__global__ void add_offsets(int* __restrict__ ptr, int* __restrict__ next,
                            const int* __restrict__ bsum, int n, int nE) {
    int i = blockIdx.x * blockDim.x + threadIdx.x;
    if (i < n) {
        int p = ptr[i] + bsum[i >> 8];
        ptr[i] = p;
        next[i] = p;
    }
    if (i == n) ptr[n] = nE;
}

__global__ void scatter_cols(const int* __restrict__ row, const int* __restrict__ col,
                             int* __restrict__ next, int* __restrict__ colS, int nE) {
    int e = blockIdx.x * blockDim.x + threadIdx.x;
    if (e < nE) {
        int pos = atomicAdd(&next[row[e]], 1);
        colS[pos] = col[e];
    }
}

// ---------------- the hop: gather segment-sum, one wave per node ----------------
// out[r][:] = sum_{e in [ptr[r],ptr[r+1])} h[colS[e]][:]
// 64 lanes x float2 = 128 floats; coalesced 512B load per edge, one store per node.
__global__ void gather_rows(const int* __restrict__ ptr, const int* __restrict__ colS,
                            const float2* __restrict__ h, float2* __restrict__ out, int n) {
    int wid  = (int)((blockIdx.x * (size_t)blockDim.x + threadIdx.x) >> 6);
    int lane = threadIdx.x & 63;
    if (wid >= n) return;
    int beg = ptr[wid], end = ptr[wid + 1];
    float2 a0 = make_float2(0.f, 0.f);
    float2 a1 = make_float2(0.f, 0.f);
    int e = beg;
    for (; e + 1 < end; e += 2) {
        int c0 = colS[e], c1 = colS[e + 1];
        float2 v0 = h[(size_t)c0 * 64 + lane];
        float2 v1 = h[(size_t)c1 * 64 + lane];
        a0.x += v0.x; a0.y += v0.y;
        a1.x += v1.x; a1.y += v1.y;
    }
    if (e < end) {
        float2 v = h[(size_t)colS[e] * 64 + lane];
        a0.x += v.x; a0.y += v.y;
    }
    a0.x += a1.x; a0.y += a1.y;
    out[(size_t)wid * 64 + lane] = a0;
}

// ---------------- fallback (round-0 atomic path) ----------------

__global__ void edge_scatter(const int* __restrict__ row, const int* __restrict__ col,
                             const float4* __restrict__ h, float* __restrict__ out, int nE) {
    int t = blockIdx.x * blockDim.x + threadIdx.x;
    int e = t >> 5;
    int q = t & 31;
    if (e < nE) {
        float4 v = h[col[e] * 32 + q];
        float* o = out + (size_t)row[e] * D_FEAT + q * 4;
        atomicAdd(o + 0, v.x);
        atomicAdd(o + 1, v.y);
        atomicAdd(o + 2, v.z);
        atomicAdd(o + 3, v.w);
    }
}

extern "C" void kernel_launch(void* const* d_in, const int* in_sizes, int n_in,
                              void* d_out, int out_size, void* d_ws, size_t ws_size,
                              hipStream_t stream) {
    const float* x    = (const float*)d_in[0];
    const float* x_id = (const float*)d_in[1];
    const int*   edge = (const int*)d_in[2];   // [2, nE]: row then col
    const int*   idx  = (const int*)d_in[3];

    int nE = in_sizes[2] / 2;
    int nN = in_sizes[3];
    const int* row = edge;
    const int* col = edge + nE;

    float* out = (float*)d_out;
    size_t hbytes = (size_t)nN * D_FEAT * sizeof(float);
    int NB = (nN + 255) / 256;   // scan blocks (must be <= 1024)

    // ---- workspace layout ----
    char* base = (char*)d_ws;
    float* h    = (float*)base;                        // hbytes
    int*   ptr  = (int*)(base + hbytes);               // nN+1
    int*   next = ptr + (nN + 1);                      // nN
    int*   bsum = next + nN;                           // NB
    int*   colS = bsum + ((NB + 3) & ~3);              // nE
    size_t needed = hbytes + sizeof(int) * ((size_t)(nN + 1) + nN + ((NB + 3) & ~3) + nE);

    int n4 = nN * D_FEAT / 4;

    if (needed > ws_size || NB > 1024) {
        // ---- fallback: round-0 atomic scatter path (needs only hbytes) ----
        hipLaunchKernelGGL(init_h0, dim3((n4 + 255) / 256), dim3(256), 0, stream,
                           (const float4*)x, (float4*)h, n4);
        hipLaunchKernelGGL(scatter_id, dim3((nN * 32 + 255) / 256), dim3(256), 0, stream,
                           (const float4*)x_id, idx, h, nN);
        long long totE = (long long)nE * 32;
        unsigned int gE = (unsigned int)((totE + 255) / 256);
        hipMemsetAsync(out, 0, hbytes, stream);
        hipLaunchKernelGGL(edge_scatter, dim3(gE), dim3(256), 0, stream,
                           row, col, (const float4*)h, out, nE);
        hipMemsetAsync(h, 0, hbytes, stream);
        hipLaunchKernelGGL(edge_scatter, dim3(gE), dim3(256), 0, stream,
                           row, col, (const float4*)out, h, nE);
        hipMemsetAsync(out, 0, hbytes, stream);
        hipLaunchKernelGGL(edge_scatter, dim3(gE), dim3(256), 0, stream,
                           row, col, (const float4*)h, out, nE);
        return;
    }

    unsigned int gEdge = (nE + 255) / 256;

    // ---- h0 = x; h0[idx] += x_id ----
    hipLaunchKernelGGL(init_h0, dim3((n4 + 255) / 256), dim3(256), 0, stream,
                       (const float4*)x, (float4*)h, n4);
    hipLaunchKernelGGL(scatter_id, dim3((nN * 32 + 255) / 256), dim3(256), 0, stream,
                       (const float4*)x_id, idx, h, nN);

    // ---- CSR build: deg -> scan -> scatter cols ----
    hipMemsetAsync(next, 0, (size_t)nN * sizeof(int), stream);  // next used as deg
    hipLaunchKernelGGL(hist_rows, dim3(gEdge), dim3(256), 0, stream, row, next, nE);
    hipLaunchKernelGGL(scan_blocks, dim3(NB), dim3(256), 0, stream, next, ptr, bsum, nN);
    hipLaunchKernelGGL(scan_bsums, dim3(1), dim3(1024), 0, stream, bsum, NB);
    hipLaunchKernelGGL(add_offsets, dim3((nN + 1 + 255) / 256), dim3(256), 0, stream,
                       ptr, next, bsum, nN, nE);
    hipLaunchKernelGGL(scatter_cols, dim3(gEdge), dim3(256), 0, stream,
                       row, col, next, colS, nE);

    // ---- 3 hops: gather segment-sum (no atomics, every row written once) ----
    unsigned int gG = (unsigned int)(((size_t)nN * 64 + 255) / 256);
    hipLaunchKernelGGL(gather_rows, dim3(gG), dim3(256), 0, stream,
                       ptr, colS, (const float2*)h, (float2*)out, nN);
    hipLaunchKernelGGL(gather_rows, dim3(gG), dim3(256), 0, stream,
                       ptr, colS, (const float2*)out, (float2*)h, nN);
    hipLaunchKernelGGL(gather_rows, dim3(gG), dim3(256), 0, stream,
                       ptr, colS, (const float2*)h, (float2*)out, nN);
}

// Round 3
// 1005.701 us; speedup vs baseline: 16.1382x; 1.2568x over previous
//
#include <hip/hip_runtime.h>

#define D_FEAT 128

// ---------------- CSR build helpers ----------------

// deg[key[e]]++ for e < n
__global__ void hist_keys(const int* __restrict__ key, int* __restrict__ deg, int n) {
    int e = blockIdx.x * blockDim.x + threadIdx.x;
    if (e < n) atomicAdd(&deg[key[e]], 1);
}

// per-256-block exclusive scan of deg -> ptrOut (partial); bsum[b] = block total
__global__ void scan_blocks(const int* __restrict__ deg, int* __restrict__ ptrOut,
                            int* __restrict__ bsum, int n) {
    __shared__ int s[256];
    int t = threadIdx.x;
    int i = blockIdx.x * 256 + t;
    int v = (i < n) ? deg[i] : 0;
    s[t] = v;
    __syncthreads();
    for (int off = 1; off < 256; off <<= 1) {
        int add = (t >= off) ? s[t - off] : 0;
        __syncthreads();
        s[t] += add;
        __syncthreads();
    }
    if (i < n) ptrOut[i] = s[t] - v;   // exclusive
    if (t == 255) bsum[blockIdx.x] = s[255];
}

// single-block exclusive scan of bsum (nb <= 1024)
__global__ void scan_bsums(int* __restrict__ bsum, int nb) {
    __shared__ int s[1024];
    int t = threadIdx.x;
    int v = (t < nb) ? bsum[t] : 0;
    s[t] = v;
    __syncthreads();
    for (int off = 1; off < 1024; off <<= 1) {
        int add = (t >= off) ? s[t - off] : 0;
        __syncthreads();
        s[t] += add;
        __syncthreads();
    }
    if (t < nb) bsum[t] = s[t] - v;    // exclusive
}

// ptr[i] += bsum[i/256]; next[i] = ptr[i]; ptr[n] = total
__global__ void add_offsets(int* __restrict__ ptr, int* __restrict__ next,
                            const int* __restrict__ bsum, int n, int total) {
    int i = blockIdx.x * blockDim.x + threadIdx.x;
    if (i < n) {
        int p = ptr[i] + bsum[i >> 8];
        ptr[i] = p;
        next[i] = p;
    }
    if (i == n) ptr[n] = total;
}

// Bucketed col scatter: bucket = blockIdx&7 (round-robin -> one XCD per bucket),
// each block strides EPB edges, handles only rows in its bucket's range.
#define EPB 2048
__global__ void scatter_cols_b(const int* __restrict__ row, const int* __restrict__ col,
                               int* __restrict__ next, int* __restrict__ colS,
                               int nE, int W) {
    int bucket = blockIdx.x & 7;
    int chunk  = blockIdx.x >> 3;
    int lo = bucket * W;
    int base = chunk * EPB;
    for (int k = threadIdx.x; k < EPB; k += 256) {
        int e = base + k;
        if (e < nE) {
            int r = row[e];
            if ((unsigned)(r - lo) < (unsigned)W) {
                int pos = atomicAdd(&next[r], 1);
                colS[pos] = col[e];
            }
        }
    }
}

// idxS[pos] = j for each j with idx[j] == n (grouped by n via inext)
__global__ void scatter_iota(const int* __restrict__ idx, int* __restrict__ inext,
                             int* __restrict__ idxS, int n) {
    int j = blockIdx.x * blockDim.x + threadIdx.x;
    if (j < n) {
        int pos = atomicAdd(&inext[idx[j]], 1);
        idxS[pos] = j;
    }
}

// h[n] = x[n] + sum_{p in [iptr[n],iptr[n+1])} x_id[idxS[p]]
// 2 nodes per wave, float4 per lane (32 lanes/node)
__global__ void init_plus_gather(const int* __restrict__ iptr, const int* __restrict__ idxS,
                                 const float4* __restrict__ x, const float4* __restrict__ x_id,
                                 float4* __restrict__ h, int n) {
    size_t tid = blockIdx.x * (size_t)blockDim.x + threadIdx.x;
    int wv   = (int)(tid >> 6);
    int lane = threadIdx.x & 63;
    int node = wv * 2 + (lane >> 5);
    int q    = lane & 31;
    if (node >= n) return;
    float4 a = x[(size_t)node * 32 + q];
    int e = iptr[node], end = iptr[node + 1];
    for (; e < end; ++e) {
        float4 v = x_id[(size_t)idxS[e] * 32 + q];
        a.x += v.x; a.y += v.y; a.z += v.z; a.w += v.w;
    }
    h[(size_t)node * 32 + q] = a;
}

// ---------------- hop: gather segment-sum ----------------
// 2 nodes per wave, float4 per lane, 4-edge unroll
__global__ void gather_rows4(const int* __restrict__ ptr, const int* __restrict__ colS,
                             const float4* __restrict__ h, float4* __restrict__ out, int n) {
    size_t tid = blockIdx.x * (size_t)blockDim.x + threadIdx.x;
    int wv   = (int)(tid >> 6);
    int lane = threadIdx.x & 63;
    int node = wv * 2 + (lane >> 5);
    int q    = lane & 31;
    if (node >= n) return;
    int e = ptr[node], end = ptr[node + 1];
    float4 a0 = make_float4(0.f, 0.f, 0.f, 0.f);
    float4 a1 = make_float4(0.f, 0.f, 0.f, 0.f);
    float4 a2 = make_float4(0.f, 0.f, 0.f, 0.f);
    float4 a3 = make_float4(0.f, 0.f, 0.f, 0.f);
    for (; e + 3 < end; e += 4) {
        int c0 = colS[e], c1 = colS[e + 1], c2 = colS[e + 2], c3 = colS[e + 3];
        float4 v0 = h[(size_t)c0 * 32 + q];
        float4 v1 = h[(size_t)c1 * 32 + q];
        float4 v2 = h[(size_t)c2 * 32 + q];
        float4 v3 = h[(size_t)c3 * 32 + q];
        a0.x += v0.x; a0.y += v0.y; a0.z += v0.z; a0.w += v0.w;
        a1.x += v1.x; a1.y += v1.y; a1.z += v1.z; a1.w += v1.w;
        a2.x += v2.x; a2.y += v2.y; a2.z += v2.z; a2.w += v2.w;
        a3.x += v3.x; a3.y += v3.y; a3.z += v3.z; a3.w += v3.w;
    }
    for (; e < end; ++e) {
        float4 v = h[(size_t)colS[e] * 32 + q];
        a0.x += v.x; a0.y += v.y; a0.z += v.z; a0.w += v.w;
    }
    a0.x += a1.x + a2.x + a3.x;
    a0.y += a1.y + a2.y + a3.y;
    a0.z += a1.z + a2.z + a3.z;
    a0.w += a1.w + a2.w + a3.w;
    out[(size_t)node * 32 + q] = a0;
}

// ---------------- fallback kernels (round-0/1 paths) ----------------

__global__ void init_h0(const float4* __restrict__ x, float4* __restrict__ h, int n4) {
    int i = blockIdx.x * blockDim.x + threadIdx.x;
    if (i < n4) h[i] = x[i];
}

__global__ void scatter_id(const float4* __restrict__ x_id, const int* __restrict__ idx,
                           float* __restrict__ h, int n) {
    int t = blockIdx.x * blockDim.x + threadIdx.x;
    int r = t >> 5;
    int q = t & 31;
    if (r < n) {
        float4 v = x_id[r * 32 + q];
        float* o = h + (size_t)idx[r] * D_FEAT + q * 4;
        atomicAdd(o + 0, v.x);
        atomicAdd(o + 1, v.y);
        atomicAdd(o + 2, v.z);
        atomicAdd(o + 3, v.w);
    }
}

__global__ void edge_scatter(const int* __restrict__ row, const int* __restrict__ col,
                             const float4* __restrict__ h, float* __restrict__ out, int nE) {
    int t = blockIdx.x * blockDim.x + threadIdx.x;
    int e = t >> 5;
    int q = t & 31;
    if (e < nE) {
        float4 v = h[col[e] * 32 + q];
        float* o = out + (size_t)row[e] * D_FEAT + q * 4;
        atomicAdd(o + 0, v.x);
        atomicAdd(o + 1, v.y);
        atomicAdd(o + 2, v.z);
        atomicAdd(o + 3, v.w);
    }
}

extern "C" void kernel_launch(void* const* d_in, const int* in_sizes, int n_in,
                              void* d_out, int out_size, void* d_ws, size_t ws_size,
                              hipStream_t stream) {
    const float* x    = (const float*)d_in[0];
    const float* x_id = (const float*)d_in[1];
    const int*   edge = (const int*)d_in[2];   // [2, nE]: row then col
    const int*   idx  = (const int*)d_in[3];

    int nE = in_sizes[2] / 2;
    int nN = in_sizes[3];
    const int* row = edge;
    const int* col = edge + nE;

    float* out = (float*)d_out;
    size_t hbytes = (size_t)nN * D_FEAT * sizeof(float);
    int NB = (nN + 255) / 256;   // scan blocks (must be <= 1024)

    // ---- workspace layout ----
    char* base = (char*)d_ws;
    float* h     = (float*)base;                        // hbytes
    int*   ptr   = (int*)(base + hbytes);               // nN+1
    int*   next  = ptr + (nN + 1);                      // nN
    int*   bsum  = next + nN;                           // NB (padded)
    int*   colS  = bsum + ((NB + 3) & ~3);              // nE
    int*   iptr  = colS + nE;                           // nN+1
    int*   inext = iptr + (nN + 1);                     // nN
    int*   ibsum = inext + nN;                          // NB (padded)
    int*   idxS  = ibsum + ((NB + 3) & ~3);             // nN
    size_t needA = hbytes + sizeof(int) * ((size_t)(nN + 1) + nN + ((NB + 3) & ~3) + nE);
    size_t needB = needA + sizeof(int) * ((size_t)(nN + 1) + nN + ((NB + 3) & ~3) + nN);

    int n4 = nN * D_FEAT / 4;
    unsigned int gEdge = (nE + 255) / 256;
    unsigned int gNode = (nN + 255) / 256;

    if (needA > ws_size || NB > 1024) {
        // ---- full fallback: atomic everything ----
        hipLaunchKernelGGL(init_h0, dim3((n4 + 255) / 256), dim3(256), 0, stream,
                           (const float4*)x, (float4*)h, n4);
        hipLaunchKernelGGL(scatter_id, dim3((nN * 32 + 255) / 256), dim3(256), 0, stream,
                           (const float4*)x_id, idx, h, nN);
        long long totE = (long long)nE * 32;
        unsigned int gE = (unsigned int)((totE + 255) / 256);
        hipMemsetAsync(out, 0, hbytes, stream);
        hipLaunchKernelGGL(edge_scatter, dim3(gE), dim3(256), 0, stream,
                           row, col, (const float4*)h, out, nE);
        hipMemsetAsync(h, 0, hbytes, stream);
        hipLaunchKernelGGL(edge_scatter, dim3(gE), dim3(256), 0, stream,
                           row, col, (const float4*)out, h, nE);
        hipMemsetAsync(out, 0, hbytes, stream);
        hipLaunchKernelGGL(edge_scatter, dim3(gE), dim3(256), 0, stream,
                           row, col, (const float4*)h, out, nE);
        return;
    }

    bool haveB = (needB <= ws_size);

    // ---- edge CSR: deg -> scan -> bucketed col scatter ----
    hipMemsetAsync(next, 0, (size_t)nN * sizeof(int), stream);
    hipLaunchKernelGGL(hist_keys, dim3(gEdge), dim3(256), 0, stream, row, next, nE);
    hipLaunchKernelGGL(scan_blocks, dim3(NB), dim3(256), 0, stream, next, ptr, bsum, nN);
    hipLaunchKernelGGL(scan_bsums, dim3(1), dim3(1024), 0, stream, bsum, NB);
    hipLaunchKernelGGL(add_offsets, dim3((nN + 1 + 255) / 256), dim3(256), 0, stream,
                       ptr, next, bsum, nN, nE);
    {
        int W = (nN + 7) / 8;
        unsigned int nChunks = (nE + EPB - 1) / EPB;
        hipLaunchKernelGGL(scatter_cols_b, dim3(nChunks * 8), dim3(256), 0, stream,
                           row, col, next, colS, nE, W);
    }

    // ---- h0 init ----
    if (haveB) {
        // CSR-invert idx, then fused init: h = x + gather(x_id)
        hipMemsetAsync(inext, 0, (size_t)nN * sizeof(int), stream);
        hipLaunchKernelGGL(hist_keys, dim3(gNode), dim3(256), 0, stream, idx, inext, nN);
        hipLaunchKernelGGL(scan_blocks, dim3(NB), dim3(256), 0, stream, inext, iptr, ibsum, nN);
        hipLaunchKernelGGL(scan_bsums, dim3(1), dim3(1024), 0, stream, ibsum, NB);
        hipLaunchKernelGGL(add_offsets, dim3((nN + 1 + 255) / 256), dim3(256), 0, stream,
                           iptr, inext, ibsum, nN, nN);
        hipLaunchKernelGGL(scatter_iota, dim3(gNode), dim3(256), 0, stream,
                           idx, inext, idxS, nN);
        unsigned int gG = (unsigned int)((((size_t)nN + 1) / 2 * 64 + 255) / 256);
        hipLaunchKernelGGL(init_plus_gather, dim3(gG), dim3(256), 0, stream,
                           iptr, idxS, (const float4*)x, (const float4*)x_id, (float4*)h, nN);
    } else {
        hipLaunchKernelGGL(init_h0, dim3((n4 + 255) / 256), dim3(256), 0, stream,
                           (const float4*)x, (float4*)h, n4);
        hipLaunchKernelGGL(scatter_id, dim3((nN * 32 + 255) / 256), dim3(256), 0, stream,
                           (const float4*)x_id, idx, h, nN);
    }

    // ---- 3 hops: gather segment-sum ----
    unsigned int gG = (unsigned int)((((size_t)nN + 1) / 2 * 64 + 255) / 256);
    hipLaunchKernelGGL(gather_rows4, dim3(gG), dim3(256), 0, stream,
                       ptr, colS, (const float4*)h, (float4*)out, nN);
    hipLaunchKernelGGL(gather_rows4, dim3(gG), dim3(256), 0, stream,
                       ptr, colS, (const float4*)out, (float4*)h, nN);
    hipLaunchKernelGGL(gather_rows4, dim3(gG), dim3(256), 0, stream,
                       ptr, colS, (const float4*)h, (float4*)out, nN);
}

// Round 4
// 651.460 us; speedup vs baseline: 24.9135x; 1.5438x over previous
//
#include <hip/hip_runtime.h>

#define D_FEAT 128
typedef unsigned int u32;

__device__ __forceinline__ float bflo(u32 w) {  // low bf16 of word -> float
    u32 b = w << 16;
    return __builtin_bit_cast(float, b);
}
__device__ __forceinline__ float bfhi(u32 w) {  // high bf16 of word -> float
    u32 b = w & 0xFFFF0000u;
    return __builtin_bit_cast(float, b);
}
__device__ __forceinline__ u32 f2bf(float f) {  // round-to-nearest-even bf16 bits
    u32 x = __builtin_bit_cast(u32, f);
    return (x + 0x7FFFu + ((x >> 16) & 1u)) >> 16;
}
__device__ __forceinline__ u32 pack2(float lo, float hi) {
    return f2bf(lo) | (f2bf(hi) << 16);
}

// ---------------- CSR build helpers ----------------

__global__ void hist_keys(const int* __restrict__ key, int* __restrict__ deg, int n) {
    int e = blockIdx.x * blockDim.x + threadIdx.x;
    if (e < n) atomicAdd(&deg[key[e]], 1);
}

__global__ void scan_blocks(const int* __restrict__ deg, int* __restrict__ ptrOut,
                            int* __restrict__ bsum, int n) {
    __shared__ int s[256];
    int t = threadIdx.x;
    int i = blockIdx.x * 256 + t;
    int v = (i < n) ? deg[i] : 0;
    s[t] = v;
    __syncthreads();
    for (int off = 1; off < 256; off <<= 1) {
        int add = (t >= off) ? s[t - off] : 0;
        __syncthreads();
        s[t] += add;
        __syncthreads();
    }
    if (i < n) ptrOut[i] = s[t] - v;
    if (t == 255) bsum[blockIdx.x] = s[255];
}

__global__ void scan_bsums(int* __restrict__ bsum, int nb) {
    __shared__ int s[1024];
    int t = threadIdx.x;
    int v = (t < nb) ? bsum[t] : 0;
    s[t] = v;
    __syncthreads();
    for (int off = 1; off < 1024; off <<= 1) {
        int add = (t >= off) ? s[t - off] : 0;
        __syncthreads();
        s[t] += add;
        __syncthreads();
    }
    if (t < nb) bsum[t] = s[t] - v;
}

__global__ void add_offsets(int* __restrict__ ptr, int* __restrict__ next,
                            const int* __restrict__ bsum, int n, int total) {
    int i = blockIdx.x * blockDim.x + threadIdx.x;
    if (i < n) {
        int p = ptr[i] + bsum[i >> 8];
        ptr[i] = p;
        next[i] = p;
    }
    if (i == n) ptr[n] = total;
}

#define EPB 2048
__global__ void scatter_cols_b(const int* __restrict__ row, const int* __restrict__ col,
                               int* __restrict__ next, int* __restrict__ colS,
                               int nE, int W) {
    int bucket = blockIdx.x & 7;
    int chunk  = blockIdx.x >> 3;
    int lo = bucket * W;
    int base = chunk * EPB;
    for (int k = threadIdx.x; k < EPB; k += 256) {
        int e = base + k;
        if (e < nE) {
            int r = row[e];
            if ((unsigned)(r - lo) < (unsigned)W) {
                int pos = atomicAdd(&next[r], 1);
                colS[pos] = col[e];
            }
        }
    }
}

__global__ void scatter_iota(const int* __restrict__ idx, int* __restrict__ inext,
                             int* __restrict__ idxS, int n) {
    int j = blockIdx.x * blockDim.x + threadIdx.x;
    if (j < n) {
        int pos = atomicAdd(&inext[idx[j]], 1);
        idxS[pos] = j;
    }
}

// h0(bf16)[n] = x[n] + sum x_id[idxS[...]]  — 2 nodes/wave, 32 lanes/node
__global__ void init_plus_gather_bf(const int* __restrict__ iptr, const int* __restrict__ idxS,
                                    const float4* __restrict__ x, const float4* __restrict__ x_id,
                                    uint2* __restrict__ h, int n) {
    size_t tid = blockIdx.x * (size_t)blockDim.x + threadIdx.x;
    int wv   = (int)(tid >> 6);
    int lane = threadIdx.x & 63;
    int node = wv * 2 + (lane >> 5);
    int q    = lane & 31;
    if (node >= n) return;
    float4 a = x[(size_t)node * 32 + q];
    int e = iptr[node], end = iptr[node + 1];
    for (; e < end; ++e) {
        float4 v = x_id[(size_t)idxS[e] * 32 + q];
        a.x += v.x; a.y += v.y; a.z += v.z; a.w += v.w;
    }
    uint2 w;
    w.x = pack2(a.x, a.y);
    w.y = pack2(a.z, a.w);
    h[(size_t)node * 32 + q] = w;
}

// ---------------- hops ----------------
// bf16 -> bf16: 2 nodes/wave, 32 lanes/node, 8B/lane (4 bf16), 4-edge unroll
__global__ void gather_bf_bf(const int* __restrict__ ptr, const int* __restrict__ colS,
                             const uint2* __restrict__ h, uint2* __restrict__ out, int n) {
    size_t tid = blockIdx.x * (size_t)blockDim.x + threadIdx.x;
    int wv   = (int)(tid >> 6);
    int lane = threadIdx.x & 63;
    int node = wv * 2 + (lane >> 5);
    int q    = lane & 31;
    if (node >= n) return;
    int e = ptr[node], end = ptr[node + 1];
    float a0 = 0.f, a1 = 0.f, a2 = 0.f, a3 = 0.f;
    float b0 = 0.f, b1 = 0.f, b2 = 0.f, b3 = 0.f;
    for (; e + 3 < end; e += 4) {
        int c0 = colS[e], c1 = colS[e + 1], c2 = colS[e + 2], c3 = colS[e + 3];
        uint2 v0 = h[(size_t)c0 * 32 + q];
        uint2 v1 = h[(size_t)c1 * 32 + q];
        uint2 v2 = h[(size_t)c2 * 32 + q];
        uint2 v3 = h[(size_t)c3 * 32 + q];
        a0 += bflo(v0.x); a1 += bfhi(v0.x); a2 += bflo(v0.y); a3 += bfhi(v0.y);
        b0 += bflo(v1.x); b1 += bfhi(v1.x); b2 += bflo(v1.y); b3 += bfhi(v1.y);
        a0 += bflo(v2.x); a1 += bfhi(v2.x); a2 += bflo(v2.y); a3 += bfhi(v2.y);
        b0 += bflo(v3.x); b1 += bfhi(v3.x); b2 += bflo(v3.y); b3 += bfhi(v3.y);
    }
    for (; e < end; ++e) {
        uint2 v = h[(size_t)colS[e] * 32 + q];
        a0 += bflo(v.x); a1 += bfhi(v.x); a2 += bflo(v.y); a3 += bfhi(v.y);
    }
    a0 += b0; a1 += b1; a2 += b2; a3 += b3;
    uint2 w;
    w.x = pack2(a0, a1);
    w.y = pack2(a2, a3);
    out[(size_t)node * 32 + q] = w;
}

// bf16 -> fp32 (final hop, writes d_out)
__global__ void gather_bf_f32(const int* __restrict__ ptr, const int* __restrict__ colS,
                              const uint2* __restrict__ h, float4* __restrict__ out, int n) {
    size_t tid = blockIdx.x * (size_t)blockDim.x + threadIdx.x;
    int wv   = (int)(tid >> 6);
    int lane = threadIdx.x & 63;
    int node = wv * 2 + (lane >> 5);
    int q    = lane & 31;
    if (node >= n) return;
    int e = ptr[node], end = ptr[node + 1];
    float a0 = 0.f, a1 = 0.f, a2 = 0.f, a3 = 0.f;
    float b0 = 0.f, b1 = 0.f, b2 = 0.f, b3 = 0.f;
    for (; e + 3 < end; e += 4) {
        int c0 = colS[e], c1 = colS[e + 1], c2 = colS[e + 2], c3 = colS[e + 3];
        uint2 v0 = h[(size_t)c0 * 32 + q];
        uint2 v1 = h[(size_t)c1 * 32 + q];
        uint2 v2 = h[(size_t)c2 * 32 + q];
        uint2 v3 = h[(size_t)c3 * 32 + q];
        a0 += bflo(v0.x); a1 += bfhi(v0.x); a2 += bflo(v0.y); a3 += bfhi(v0.y);
        b0 += bflo(v1.x); b1 += bfhi(v1.x); b2 += bflo(v1.y); b3 += bfhi(v1.y);
        a0 += bflo(v2.x); a1 += bfhi(v2.x); a2 += bflo(v2.y); a3 += bfhi(v2.y);
        b0 += bflo(v3.x); b1 += bfhi(v3.x); b2 += bflo(v3.y); b3 += bfhi(v3.y);
    }
    for (; e < end; ++e) {
        uint2 v = h[(size_t)colS[e] * 32 + q];
        a0 += bflo(v.x); a1 += bfhi(v.x); a2 += bflo(v.y); a3 += bfhi(v.y);
    }
    float4 w;
    w.x = a0 + b0; w.y = a1 + b1; w.z = a2 + b2; w.w = a3 + b3;
    out[(size_t)node * 32 + q] = w;
}

// ---------------- fallback kernels (round-0 atomic fp32 path) ----------------

__global__ void init_h0(const float4* __restrict__ x, float4* __restrict__ h, int n4) {
    int i = blockIdx.x * blockDim.x + threadIdx.x;
    if (i < n4) h[i] = x[i];
}

__global__ void scatter_id(const float4* __restrict__ x_id, const int* __restrict__ idx,
                           float* __restrict__ h, int n) {
    int t = blockIdx.x * blockDim.x + threadIdx.x;
    int r = t >> 5;
    int q = t & 31;
    if (r < n) {
        float4 v = x_id[r * 32 + q];
        float* o = h + (size_t)idx[r] * D_FEAT + q * 4;
        atomicAdd(o + 0, v.x);
        atomicAdd(o + 1, v.y);
        atomicAdd(o + 2, v.z);
        atomicAdd(o + 3, v.w);
    }
}

__global__ void edge_scatter(const int* __restrict__ row, const int* __restrict__ col,
                             const float4* __restrict__ h, float* __restrict__ out, int nE) {
    int t = blockIdx.x * blockDim.x + threadIdx.x;
    int e = t >> 5;
    int q = t & 31;
    if (e < nE) {
        float4 v = h[col[e] * 32 + q];
        float* o = out + (size_t)row[e] * D_FEAT + q * 4;
        atomicAdd(o + 0, v.x);
        atomicAdd(o + 1, v.y);
        atomicAdd(o + 2, v.z);
        atomicAdd(o + 3, v.w);
    }
}

extern "C" void kernel_launch(void* const* d_in, const int* in_sizes, int n_in,
                              void* d_out, int out_size, void* d_ws, size_t ws_size,
                              hipStream_t stream) {
    const float* x    = (const float*)d_in[0];
    const float* x_id = (const float*)d_in[1];
    const int*   edge = (const int*)d_in[2];   // [2, nE]: row then col
    const int*   idx  = (const int*)d_in[3];

    int nE = in_sizes[2] / 2;
    int nN = in_sizes[3];
    const int* row = edge;
    const int* col = edge + nE;

    float* out = (float*)d_out;
    size_t hbytes  = (size_t)nN * D_FEAT * sizeof(float);  // fp32 row buffer
    size_t hbbytes = (size_t)nN * D_FEAT * 2;              // bf16 row buffer
    int NB = (nN + 255) / 256;

    // ---- workspace layout: two bf16 buffers + CSR ints ----
    char* base = (char*)d_ws;
    uint2* hb0  = (uint2*)base;                            // hbbytes
    uint2* hb1  = (uint2*)(base + hbbytes);                // hbbytes
    int*   ptr   = (int*)(base + 2 * hbbytes);             // nN+1
    int*   next  = ptr + (nN + 1);                         // nN
    int*   bsum  = next + nN;                              // NB (padded)
    int*   colS  = bsum + ((NB + 3) & ~3);                 // nE
    int*   iptr  = colS + nE;                              // nN+1
    int*   inext = iptr + (nN + 1);                        // nN
    int*   ibsum = inext + nN;                             // NB (padded)
    int*   idxS  = ibsum + ((NB + 3) & ~3);                // nN
    size_t needBF = 2 * hbbytes + sizeof(int) *
        ((size_t)(nN + 1) * 2 + (size_t)nN * 2 + 2 * ((NB + 3) & ~3) + nE + nN);

    int n4 = nN * D_FEAT / 4;
    unsigned int gEdge = (nE + 255) / 256;
    unsigned int gNode = (nN + 255) / 256;

    if (needBF > ws_size || NB > 1024) {
        // ---- fallback: atomic fp32 path (needs only hbytes) ----
        float* h = (float*)d_ws;
        hipLaunchKernelGGL(init_h0, dim3((n4 + 255) / 256), dim3(256), 0, stream,
                           (const float4*)x, (float4*)h, n4);
        hipLaunchKernelGGL(scatter_id, dim3((nN * 32 + 255) / 256), dim3(256), 0, stream,
                           (const float4*)x_id, idx, h, nN);
        long long totE = (long long)nE * 32;
        unsigned int gE = (unsigned int)((totE + 255) / 256);
        hipMemsetAsync(out, 0, hbytes, stream);
        hipLaunchKernelGGL(edge_scatter, dim3(gE), dim3(256), 0, stream,
                           row, col, (const float4*)h, out, nE);
        hipMemsetAsync(h, 0, hbytes, stream);
        hipLaunchKernelGGL(edge_scatter, dim3(gE), dim3(256), 0, stream,
                           row, col, (const float4*)out, h, nE);
        hipMemsetAsync(out, 0, hbytes, stream);
        hipLaunchKernelGGL(edge_scatter, dim3(gE), dim3(256), 0, stream,
                           row, col, (const float4*)h, out, nE);
        return;
    }

    // ---- edge CSR ----
    hipMemsetAsync(next, 0, (size_t)nN * sizeof(int), stream);
    hipLaunchKernelGGL(hist_keys, dim3(gEdge), dim3(256), 0, stream, row, next, nE);
    hipLaunchKernelGGL(scan_blocks, dim3(NB), dim3(256), 0, stream, next, ptr, bsum, nN);
    hipLaunchKernelGGL(scan_bsums, dim3(1), dim3(1024), 0, stream, bsum, NB);
    hipLaunchKernelGGL(add_offsets, dim3((nN + 1 + 255) / 256), dim3(256), 0, stream,
                       ptr, next, bsum, nN, nE);
    {
        int W = (nN + 7) / 8;
        unsigned int nChunks = (nE + EPB - 1) / EPB;
        hipLaunchKernelGGL(scatter_cols_b, dim3(nChunks * 8), dim3(256), 0, stream,
                           row, col, next, colS, nE, W);
    }

    // ---- idx inversion + fused bf16 init ----
    hipMemsetAsync(inext, 0, (size_t)nN * sizeof(int), stream);
    hipLaunchKernelGGL(hist_keys, dim3(gNode), dim3(256), 0, stream, idx, inext, nN);
    hipLaunchKernelGGL(scan_blocks, dim3(NB), dim3(256), 0, stream, inext, iptr, ibsum, nN);
    hipLaunchKernelGGL(scan_bsums, dim3(1), dim3(1024), 0, stream, ibsum, NB);
    hipLaunchKernelGGL(add_offsets, dim3((nN + 1 + 255) / 256), dim3(256), 0, stream,
                       iptr, inext, ibsum, nN, nN);
    hipLaunchKernelGGL(scatter_iota, dim3(gNode), dim3(256), 0, stream,
                       idx, inext, idxS, nN);

    unsigned int gG = (unsigned int)((((size_t)nN + 1) / 2 * 64 + 255) / 256);
    hipLaunchKernelGGL(init_plus_gather_bf, dim3(gG), dim3(256), 0, stream,
                       iptr, idxS, (const float4*)x, (const float4*)x_id, hb0, nN);

    // ---- hops: bf16 -> bf16 -> bf16 -> fp32(out) ----
    hipLaunchKernelGGL(gather_bf_bf, dim3(gG), dim3(256), 0, stream,
                       ptr, colS, (const uint2*)hb0, hb1, nN);
    hipLaunchKernelGGL(gather_bf_bf, dim3(gG), dim3(256), 0, stream,
                       ptr, colS, (const uint2*)hb1, hb0, nN);
    hipLaunchKernelGGL(gather_bf_f32, dim3(gG), dim3(256), 0, stream,
                       ptr, colS, (const uint2*)hb0, (float4*)out, nN);
}